// Round 11
// baseline (3598.659 us; speedup 1.0000x reference)
//
#include <hip/hip_runtime.h>

// Problem constants (ManyChannelsIntegrator: C=2, B=256, T=256, N=2048)
#define NN 2048
#define BB 256
#define TT 256
#define SLOPE 8.0f

#define NBLK 256   // 1 block per CU
#define NTH  512   // 8 waves: (msub 2) x (kq 4)
#define MT 64      // b-rows per block  (gM = 4)
#define NT 32      // n-cols per block  (gN = 64)
#define NSB 8      // S-buffer rotation depth (invalidate every NSB steps)

// LDS layout (bytes)
#define LDS_W    0                         // W in B-frag order (32x32x16): 128 chunks x 1 KB = 128 KB
#define PRE_STRIDE 36                      // fp32 words per row
#define LDS_R1   131072                    // [2 msub][32][36] fp32 — kq0+kq1 partial
#define LDS_R3   (LDS_R1 + 2*32*PRE_STRIDE*4)   // [2 msub][32][36] — kq2+kq3 partial
#define LDS_CONST (LDS_R3 + 2*32*PRE_STRIDE*4)
#define LDS_TOTAL (LDS_CONST + 7*32*4)          // 150400 < 160 KB

// ws layout (bytes)
#define WS_FLAGS 0                       // [4 bm][64 member][4 sub] u32 = 4096 B (memset 0)
#define WS_SBUF  4096                    // 8 x 1 MB S rotation, A-frag order (32x32)
#define WS_PART  (4096 + (8u<<20))       // u32-packed bf16 partials [T][64 bn][256 b]

typedef short s16x8 __attribute__((ext_vector_type(8)));      // 8 bf16 (4 VGPRs)
typedef float f32x16 __attribute__((ext_vector_type(16)));
typedef unsigned u32x4 __attribute__((ext_vector_type(4)));

__device__ __forceinline__ unsigned f2bf1(float f) {
  union { float f; unsigned u; } v; v.f = f;
  return (v.u + 0x7fffu + ((v.u >> 16) & 1u)) >> 16;   // RNE
}
__device__ __forceinline__ unsigned pack2(float a, float b) {
  return f2bf1(a) | (f2bf1(b) << 16);
}

// System-scope write-through stores (never dirty L1/L2 -> buffer_inv safe).
__device__ __forceinline__ void store_b128_sys(void* p, u32x4 v) {
  asm volatile("global_store_dwordx4 %0, %1, off sc0 sc1" :: "v"(p), "v"(v) : "memory");
}
__device__ __forceinline__ void store_u32_sys(void* p, unsigned v) {
  asm volatile("global_store_dword %0, %1, off sc0 sc1" :: "v"(p), "v"(v) : "memory");
}

// A-load: plain -> L1/L2-cached (R7/R10: L2 dedups the broadcast).
#define LOAD_A(dst, base, OFF) \
  asm volatile("global_load_dwordx4 %0, %1, off offset:" #OFF \
               : "=v"(dst) : "v"(base) : "memory")

__global__ __launch_bounds__(NTH, 2)
void mc_integrator_kernel(const float* __restrict__ x, const float* __restrict__ state0,
                          const float* __restrict__ mask, const float* __restrict__ enc,
                          const float* __restrict__ dec, const float* __restrict__ W,
                          const float* __restrict__ bias, const float* __restrict__ thr,
                          char* __restrict__ ws)
{
  extern __shared__ char lds[];
  const int tid = threadIdx.x;
  const int blk = blockIdx.x;
  // blk%8 ~ XCD: group bm occupies XCDs {2bm, 2bm+1} exclusively.
  const int xcd  = blk & 7;
  const int slot = blk >> 3;
  const int bm = xcd >> 1;                      // 0..3  (64-row strip of b)
  const int bn = slot + ((xcd & 1) << 5);       // 0..63 (32-col strip of n)

  unsigned* flags = (unsigned*)(ws + WS_FLAGS);   // [(bm*64+member)*4 + sub]
  char* sbufs = ws + WS_SBUF;                     // 8 x 1 MB rotation
  unsigned* partials = (unsigned*)(ws + WS_PART);

  // ---- stage per-n constants ----
  float* cmask = (float*)(lds + LDS_CONST);
  float* cbias = cmask + 32;  float* cthr  = cbias + 32;
  float* cenc0 = cthr  + 32;  float* cenc1 = cenc0 + 32;
  float* cdec0 = cenc1 + 32;  float* cdec1 = cdec0 + 32;
  if (tid < 32) {
    int n = bn * NT + tid;
    cmask[tid] = mask[n];  cbias[tid] = bias[n];  cthr[tid] = thr[n];
    cenc0[tid] = enc[n];   cenc1[tid] = enc[NN + n];
    cdec0[tid] = dec[n];   cdec1[tid] = dec[NN + n];
  }

  // ---- one-time: W tile -> bf16, LDS, 32x32x16 B-frag order (R9-validated) ----
  for (int it = 0; it < 16; ++it) {
    int c = tid + it * NTH;              // 0..8191
    int n_local = c >> 8;                // 0..31
    int kc = c & 255;                    // 8-k unit
    int k0 = kc * 8;
    const float* src = W + (size_t)(bn * NT + n_local) * NN + k0;
    float4 lo = *(const float4*)src;
    float4 hi = *(const float4*)(src + 4);
    u32x4 pk = { pack2(lo.x, lo.y), pack2(lo.z, lo.w),
                 pack2(hi.x, hi.y), pack2(hi.z, hi.w) };
    int addr = (kc >> 1) * 1024 + (((kc & 1) << 5) + n_local) * 16;
    *(u32x4*)(lds + LDS_W + addr) = pk;
  }
  __syncthreads();

  // ---- per-thread epilogue roles ----
  const int b_local = (tid & 255) >> 2;          // 0..63
  const int c4      = tid & 3;                   // 8-col group of n
  const int bg      = bm * MT + b_local;
  const int nl0     = c4 * 8;
  // S A-frag slot (32x32, R9-validated)
  const int rg     = bg >> 5;
  const int kb16_s = bn * 2 + (c4 >> 1);
  const int lane_s = ((c4 & 1) << 5) | (bg & 31);
  const unsigned s_slot = (unsigned)((rg * 128 + kb16_s) * 1024 + lane_s * 16);

  // ---- build S_0 -> sbuf[0], post subflags (value 1) ----
  if (tid < 256) {
    const float* s0 = state0 + (size_t)bg * NN + bn * NT + nl0;
    float4 lo = *(const float4*)s0;
    float4 hi = *(const float4*)(s0 + 4);
    float sv[8] = {lo.x, lo.y, lo.z, lo.w, hi.x, hi.y, hi.z, hi.w};
    float x0 = x[(size_t)bg * TT];
    float x1 = x[(size_t)(BB*TT) + bg * TT];
    #pragma unroll
    for (int j = 0; j < 8; ++j)
      sv[j] += cmask[nl0+j] * (x0 * cenc0[nl0+j] + x1 * cenc1[nl0+j]);
    u32x4 pk = { pack2(sv[0], sv[1]), pack2(sv[2], sv[3]),
                 pack2(sv[4], sv[5]), pack2(sv[6], sv[7]) };
    store_b128_sys(sbufs + s_slot, pk);
    asm volatile("s_waitcnt vmcnt(0)" ::: "memory");
    if ((tid & 63) == 0)
      __hip_atomic_store(&flags[(bm*64 + bn)*4 + (tid >> 6)], 1u,
                         __ATOMIC_RELAXED, __HIP_MEMORY_SCOPE_SYSTEM);
  }
  // phase-anchor fence: invalidate stale (poison-era) lines before first loads
  __syncthreads();
  if (tid < 64) __builtin_amdgcn_fence(__ATOMIC_ACQUIRE, "agent");
  __syncthreads();

  // ---- persistent time loop ----
  const int wave = tid >> 6, lane = tid & 63;
  const int msub = wave & 1;      // 32-row group
  const int kq   = wave >> 1;     // k-quarter (512)
  const unsigned a_off = (unsigned)((((bm*2 + msub) * 128) + kq * 32) * 1024 + lane * 16);
  const unsigned w_off = (unsigned)(LDS_W + (kq * 32) * 1024 + lane * 16);
  // C/D frag address pieces (32x32): col=lane&31, row=(r&3)+8*(r>>2)+4*(lane>>5)
  const int rowb = 4 * (lane >> 5);
  const int colc = lane & 31;
  float* reg1 = (float*)(lds + LDS_R1) + msub * 32 * PRE_STRIDE;
  float* reg3 = (float*)(lds + LDS_R3) + msub * 32 * PRE_STRIDE;
  // my quarter's producers: blocks bn in [16*kq, 16*kq+16); lane L polls
  // subflag (producer L>>2, sub L&3) — 64 lanes cover 16 producers x 4 subs.
  const unsigned fidx = (unsigned)((bm*64 + 16*kq + (lane >> 2))*4 + (lane & 3));

  for (int t = 0; t < TT; ++t) {
    const char* sb = sbufs + ((unsigned)(t & (NSB-1)) << 20);
    char*       sn = sbufs + ((unsigned)((t+1) & (NSB-1)) << 20);

    // ---- per-wave wait: only MY quarter's 16 producers ----
    {
      const unsigned tv = (unsigned)(t + 1);
      for (;;) {
        unsigned v = __hip_atomic_load(&flags[fidx], __ATOMIC_RELAXED, __HIP_MEMORY_SCOPE_SYSTEM);
        if (__all(v >= tv)) break;
        __builtin_amdgcn_s_sleep(1);
      }
    }

    // ---- A-phase: 32 chunks, 16-slot register ring, vmcnt(8) phases ----
    f32x16 acc = {0,0,0,0,0,0,0,0,0,0,0,0,0,0,0,0};
    const char* ap = sb + a_off;
    s16x8 Ar[16];
    #pragma unroll
    for (int g = 0; g < 4; ++g) {
      const char* base = ap + g * 4096;
      LOAD_A(Ar[g*4+0], base, 0);
      LOAD_A(Ar[g*4+1], base, 1024);
      LOAD_A(Ar[g*4+2], base, 2048);
      LOAD_A(Ar[g*4+3], base, 3072);
    }
    asm volatile("s_waitcnt vmcnt(8)"
      : "+v"(Ar[0]),"+v"(Ar[1]),"+v"(Ar[2]),"+v"(Ar[3]),
        "+v"(Ar[4]),"+v"(Ar[5]),"+v"(Ar[6]),"+v"(Ar[7]));
    #pragma unroll
    for (int i = 0; i < 8; ++i) {
      s16x8 b = *(const s16x8*)(lds + w_off + i * 1024);
      acc = __builtin_amdgcn_mfma_f32_32x32x16_bf16(Ar[i], b, acc, 0, 0, 0);
    }
    {
      const char* b0 = ap + 16384;
      LOAD_A(Ar[0], b0, 0); LOAD_A(Ar[1], b0, 1024);
      LOAD_A(Ar[2], b0, 2048); LOAD_A(Ar[3], b0, 3072);
      const char* b1 = ap + 20480;
      LOAD_A(Ar[4], b1, 0); LOAD_A(Ar[5], b1, 1024);
      LOAD_A(Ar[6], b1, 2048); LOAD_A(Ar[7], b1, 3072);
    }
    asm volatile("s_waitcnt vmcnt(8)"
      : "+v"(Ar[8]),"+v"(Ar[9]),"+v"(Ar[10]),"+v"(Ar[11]),
        "+v"(Ar[12]),"+v"(Ar[13]),"+v"(Ar[14]),"+v"(Ar[15]));
    #pragma unroll
    for (int i = 8; i < 16; ++i) {
      s16x8 b = *(const s16x8*)(lds + w_off + i * 1024);
      acc = __builtin_amdgcn_mfma_f32_32x32x16_bf16(Ar[i], b, acc, 0, 0, 0);
    }
    {
      const char* b0 = ap + 24576;
      LOAD_A(Ar[8], b0, 0);  LOAD_A(Ar[9], b0, 1024);
      LOAD_A(Ar[10], b0, 2048); LOAD_A(Ar[11], b0, 3072);
      const char* b1 = ap + 28672;
      LOAD_A(Ar[12], b1, 0); LOAD_A(Ar[13], b1, 1024);
      LOAD_A(Ar[14], b1, 2048); LOAD_A(Ar[15], b1, 3072);
    }
    asm volatile("s_waitcnt vmcnt(8)"
      : "+v"(Ar[0]),"+v"(Ar[1]),"+v"(Ar[2]),"+v"(Ar[3]),
        "+v"(Ar[4]),"+v"(Ar[5]),"+v"(Ar[6]),"+v"(Ar[7]));
    #pragma unroll
    for (int i = 16; i < 24; ++i) {
      s16x8 b = *(const s16x8*)(lds + w_off + i * 1024);
      acc = __builtin_amdgcn_mfma_f32_32x32x16_bf16(Ar[i - 16], b, acc, 0, 0, 0);
    }
    asm volatile("s_waitcnt vmcnt(0)"
      : "+v"(Ar[8]),"+v"(Ar[9]),"+v"(Ar[10]),"+v"(Ar[11]),
        "+v"(Ar[12]),"+v"(Ar[13]),"+v"(Ar[14]),"+v"(Ar[15]));
    #pragma unroll
    for (int i = 24; i < 32; ++i) {
      s16x8 b = *(const s16x8*)(lds + w_off + i * 1024);
      acc = __builtin_amdgcn_mfma_f32_32x32x16_bf16(Ar[i - 16], b, acc, 0, 0, 0);
    }

    // ---- 2-phase race-free k-merge ----
    __syncthreads();   // SB1: prev epilogue reads done; all accs ready
    if (kq == 1) {
      #pragma unroll
      for (int r = 0; r < 16; ++r) {
        int row = rowb + (r & 3) + 8 * (r >> 2);
        reg1[row * PRE_STRIDE + colc] = acc[r];
      }
    } else if (kq == 3) {
      #pragma unroll
      for (int r = 0; r < 16; ++r) {
        int row = rowb + (r & 3) + 8 * (r >> 2);
        reg3[row * PRE_STRIDE + colc] = acc[r];
      }
    }
    __syncthreads();   // SB2
    if (kq == 0) {
      #pragma unroll
      for (int r = 0; r < 16; ++r) {
        int row = rowb + (r & 3) + 8 * (r >> 2);
        reg1[row * PRE_STRIDE + colc] += acc[r];
      }
    } else if (kq == 2) {
      #pragma unroll
      for (int r = 0; r < 16; ++r) {
        int row = rowb + (r & 3) + 8 * (r >> 2);
        reg3[row * PRE_STRIDE + colc] += acc[r];
      }
    }
    __syncthreads();   // SB3
    // Rotation fence (every NSB steps) at the rendezvous, BEFORE any wave
    // races ahead into the reused buffer slot.
    if (t < TT - 1 && ((t + 1) & (NSB - 1)) == 0) {
      if (tid < 64) __builtin_amdgcn_fence(__ATOMIC_ACQUIRE, "agent");
      __syncthreads();
    }

    // ---- epilogue on waves 0-3 only; waves 4-7 race ahead to t+1 poll ----
    if (tid < 256) {
      const float* p1 = (const float*)(lds + LDS_R1) + b_local * PRE_STRIDE + nl0;
      const float* p3 = (const float*)(lds + LDS_R3) + b_local * PRE_STRIDE + nl0;
      float4 u0 = *(const float4*)p1, u1 = *(const float4*)(p1 + 4);
      float4 v0 = *(const float4*)p3, v1 = *(const float4*)(p3 + 4);
      float pr[8] = {u0.x+v0.x, u0.y+v0.y, u0.z+v0.z, u0.w+v0.w,
                     u1.x+v1.x, u1.y+v1.y, u1.z+v1.z, u1.w+v1.w};
      float st[8];
      float d0 = 0.f, d1 = 0.f;
      #pragma unroll
      for (int j = 0; j < 8; ++j) {
        int nl = nl0 + j;
        float sg = 1.0f / (1.0f + __expf(-SLOPE * (pr[j] - cthr[nl])));
        float s = cmask[nl] * (cbias[nl] + sg);
        st[j] = s;
        d0 += s * cdec0[nl];
        d1 += s * cdec1[nl];
      }
      d0 += __shfl_xor(d0, 1); d0 += __shfl_xor(d0, 2);
      d1 += __shfl_xor(d1, 1); d1 += __shfl_xor(d1, 2);
      if (c4 == 0)
        store_u32_sys(&partials[((size_t)t*64 + bn)*256 + bg], pack2(d0, d1));
      if (t < TT - 1) {
        float x0n = x[(size_t)bg * TT + t + 1];
        float x1n = x[(size_t)(BB*TT) + bg * TT + t + 1];
        float sv[8];
        #pragma unroll
        for (int j = 0; j < 8; ++j) {
          int nl = nl0 + j;
          sv[j] = st[j] + cmask[nl] * (x0n * cenc0[nl] + x1n * cenc1[nl]);
        }
        u32x4 pk = { pack2(sv[0], sv[1]), pack2(sv[2], sv[3]),
                     pack2(sv[4], sv[5]), pack2(sv[6], sv[7]) };
        store_b128_sys(sn + s_slot, pk);
        // per-wave completion post: drain own stores, post this wave's subflag
        asm volatile("s_waitcnt vmcnt(0)" ::: "memory");
        if ((tid & 63) == 0)
          __hip_atomic_store(&flags[(bm*64 + bn)*4 + (tid >> 6)], (unsigned)(t + 2),
                             __ATOMIC_RELAXED, __HIP_MEMORY_SCOPE_SYSTEM);
      }
    }
  }
}

// out[c][b][t] = sum_bn unpack(partials[t][bn][b])
__global__ __launch_bounds__(256)
void reduce_out_kernel(const unsigned* __restrict__ partials, float* __restrict__ out) {
  const int t = blockIdx.x;
  const int b = threadIdx.x;
  const unsigned* p = partials + (size_t)t * 64 * 256 + b;
  float s0 = 0.f, s1 = 0.f;
  #pragma unroll
  for (int bn = 0; bn < 64; ++bn) {
    unsigned v = p[bn * 256];
    union { unsigned u; float f; } lo, hi;
    lo.u = v << 16; hi.u = v & 0xffff0000u;
    s0 += lo.f; s1 += hi.f;
  }
  out[(size_t)b * TT + t] = s0;
  out[(size_t)(BB * TT) + (size_t)b * TT + t] = s1;
}

extern "C" void kernel_launch(void* const* d_in, const int* in_sizes, int n_in,
                              void* d_out, int out_size, void* d_ws, size_t ws_size,
                              hipStream_t stream) {
  const float* x      = (const float*)d_in[0];
  const float* state0 = (const float*)d_in[1];
  const float* mask   = (const float*)d_in[2];
  const float* enc    = (const float*)d_in[3];
  const float* dec    = (const float*)d_in[4];
  const float* W      = (const float*)d_in[5];
  const float* bias   = (const float*)d_in[6];
  const float* thr    = (const float*)d_in[7];
  float* out = (float*)d_out;
  char*  ws  = (char*)d_ws;

  (void)hipMemsetAsync(ws, 0, 4096, stream);   // subflags [4][64][4]

  (void)hipFuncSetAttribute((const void*)mc_integrator_kernel,
                            hipFuncAttributeMaxDynamicSharedMemorySize, LDS_TOTAL);

  void* args[] = { (void*)&x, (void*)&state0, (void*)&mask, (void*)&enc, (void*)&dec,
                   (void*)&W, (void*)&bias, (void*)&thr, (void*)&ws };
  (void)hipLaunchCooperativeKernel((const void*)mc_integrator_kernel,
                                   dim3(NBLK), dim3(NTH), args, (unsigned)LDS_TOTAL, stream);

  const unsigned* partials = (const unsigned*)(ws + WS_PART);
  reduce_out_kernel<<<dim3(TT), dim3(256), 0, stream>>>(partials, out);
}

// Round 12
// 2685.964 us; speedup vs baseline: 1.3398x; 1.3398x over previous
//
#include <hip/hip_runtime.h>

// Problem constants (ManyChannelsIntegrator: C=2, B=256, T=256, N=2048)
#define NN 2048
#define BB 256
#define TT 256
#define SLOPE 8.0f

#define NBLK 256   // 1 block per CU
#define NTH  512   // 8 waves: (msub 2) x (kq 4)
#define MT 64      // b-rows per block  (gM = 4)
#define NT 32      // n-cols per block  (gN = 64)
#define NSB 8      // S-buffer rotation depth (invalidate every NSB steps)

// LDS layout (bytes)
#define LDS_W    0                         // W in B-frag order (32x32x16): 128 chunks x 1 KB = 128 KB
#define PRE_STRIDE 36                      // fp32 words per row
#define LDS_R1   131072                    // [2 msub][32][36] fp32 — kq0+kq1 partial
#define LDS_R3   (LDS_R1 + 2*32*PRE_STRIDE*4)   // [2 msub][32][36] — kq2+kq3 partial
#define LDS_CONST (LDS_R3 + 2*32*PRE_STRIDE*4)
#define LDS_TOTAL (LDS_CONST + 7*32*4)          // 150400 < 160 KB

// ws layout (bytes)
#define WS_FLAGS 0                       // [4 bm][64 member][4 sub] u32 = 4096 B (memset 0)
#define WS_SBUF  4096                    // 8 x 1 MB S rotation, A-frag order (32x32)
#define WS_PART  (4096 + (8u<<20))       // u32-packed bf16 partials [T][64 bn][256 b]

typedef short s16x8 __attribute__((ext_vector_type(8)));      // 8 bf16 (4 VGPRs)
typedef float f32x16 __attribute__((ext_vector_type(16)));
typedef unsigned u32x4 __attribute__((ext_vector_type(4)));

__device__ __forceinline__ unsigned f2bf1(float f) {
  union { float f; unsigned u; } v; v.f = f;
  return (v.u + 0x7fffu + ((v.u >> 16) & 1u)) >> 16;   // RNE
}
__device__ __forceinline__ unsigned pack2(float a, float b) {
  return f2bf1(a) | (f2bf1(b) << 16);
}

// System-scope write-through stores (never dirty L1/L2 -> buffer_inv safe).
__device__ __forceinline__ void store_b128_sys(void* p, u32x4 v) {
  asm volatile("global_store_dwordx4 %0, %1, off sc0 sc1" :: "v"(p), "v"(v) : "memory");
}
__device__ __forceinline__ void store_u32_sys(void* p, unsigned v) {
  asm volatile("global_store_dword %0, %1, off sc0 sc1" :: "v"(p), "v"(v) : "memory");
}

// A-load: plain -> L1/L2-cached (R7/R10: L2 dedups the broadcast).
#define LOAD_A(dst, base, OFF) \
  asm volatile("global_load_dwordx4 %0, %1, off offset:" #OFF \
               : "=v"(dst) : "v"(base) : "memory")

__global__ __launch_bounds__(NTH, 2)
void mc_integrator_kernel(const float* __restrict__ x, const float* __restrict__ state0,
                          const float* __restrict__ mask, const float* __restrict__ enc,
                          const float* __restrict__ dec, const float* __restrict__ W,
                          const float* __restrict__ bias, const float* __restrict__ thr,
                          char* __restrict__ ws)
{
  extern __shared__ char lds[];
  const int tid = threadIdx.x;
  const int blk = blockIdx.x;
  // blk%8 ~ XCD: group bm occupies XCDs {2bm, 2bm+1} exclusively.
  const int xcd  = blk & 7;
  const int slot = blk >> 3;
  const int bm = xcd >> 1;                      // 0..3  (64-row strip of b)
  const int bn = slot + ((xcd & 1) << 5);       // 0..63 (32-col strip of n)

  unsigned* flags = (unsigned*)(ws + WS_FLAGS);   // [(bm*64+member)*4 + sub]
  char* sbufs = ws + WS_SBUF;                     // 8 x 1 MB rotation
  unsigned* partials = (unsigned*)(ws + WS_PART);

  // ---- stage per-n constants ----
  float* cmask = (float*)(lds + LDS_CONST);
  float* cbias = cmask + 32;  float* cthr  = cbias + 32;
  float* cenc0 = cthr  + 32;  float* cenc1 = cenc0 + 32;
  float* cdec0 = cenc1 + 32;  float* cdec1 = cdec0 + 32;
  if (tid < 32) {
    int n = bn * NT + tid;
    cmask[tid] = mask[n];  cbias[tid] = bias[n];  cthr[tid] = thr[n];
    cenc0[tid] = enc[n];   cenc1[tid] = enc[NN + n];
    cdec0[tid] = dec[n];   cdec1[tid] = dec[NN + n];
  }

  // ---- one-time: W tile -> bf16, LDS, 32x32x16 B-frag order (R9-validated) ----
  for (int it = 0; it < 16; ++it) {
    int c = tid + it * NTH;              // 0..8191
    int n_local = c >> 8;                // 0..31
    int kc = c & 255;                    // 8-k unit
    int k0 = kc * 8;
    const float* src = W + (size_t)(bn * NT + n_local) * NN + k0;
    float4 lo = *(const float4*)src;
    float4 hi = *(const float4*)(src + 4);
    u32x4 pk = { pack2(lo.x, lo.y), pack2(lo.z, lo.w),
                 pack2(hi.x, hi.y), pack2(hi.z, hi.w) };
    int addr = (kc >> 1) * 1024 + (((kc & 1) << 5) + n_local) * 16;
    *(u32x4*)(lds + LDS_W + addr) = pk;
  }
  __syncthreads();

  // ---- per-thread epilogue roles ----
  const int b_local = (tid & 255) >> 2;          // 0..63
  const int c4      = tid & 3;                   // 8-col group of n
  const int bg      = bm * MT + b_local;
  const int nl0     = c4 * 8;
  // S A-frag slot (32x32, R9-validated)
  const int rg     = bg >> 5;
  const int kb16_s = bn * 2 + (c4 >> 1);
  const int lane_s = ((c4 & 1) << 5) | (bg & 31);
  const unsigned s_slot = (unsigned)((rg * 128 + kb16_s) * 1024 + lane_s * 16);

  // ---- build S_0 -> sbuf[0]; early per-wave subflag post (value 1) ----
  if (tid < 256) {
    const float* s0 = state0 + (size_t)bg * NN + bn * NT + nl0;
    float4 lo = *(const float4*)s0;
    float4 hi = *(const float4*)(s0 + 4);
    float sv[8] = {lo.x, lo.y, lo.z, lo.w, hi.x, hi.y, hi.z, hi.w};
    float x0 = x[(size_t)bg * TT];
    float x1 = x[(size_t)(BB*TT) + bg * TT];
    #pragma unroll
    for (int j = 0; j < 8; ++j)
      sv[j] += cmask[nl0+j] * (x0 * cenc0[nl0+j] + x1 * cenc1[nl0+j]);
    u32x4 pk = { pack2(sv[0], sv[1]), pack2(sv[2], sv[3]),
                 pack2(sv[4], sv[5]), pack2(sv[6], sv[7]) };
    store_b128_sys(sbufs + s_slot, pk);
    asm volatile("s_waitcnt vmcnt(0)" ::: "memory");
    if ((tid & 63) == 0)
      __hip_atomic_store(&flags[(bm*64 + bn)*4 + (tid >> 6)], 1u,
                         __ATOMIC_RELAXED, __HIP_MEMORY_SCOPE_SYSTEM);
  }
  // wave 4 polls the whole group (64 members x 4 subs = dwordx4 per lane)
  if ((tid >> 6) == 4) {
    const unsigned* fp = &flags[(bm*64 + (tid & 63)) * 4];
    for (;;) {
      u32x4 v;
      asm volatile("global_load_dwordx4 %0, %1, off sc0 sc1" : "=v"(v) : "v"(fp) : "memory");
      asm volatile("s_waitcnt vmcnt(0)" : "+v"(v));
      if (__all(v[0] >= 1u && v[1] >= 1u && v[2] >= 1u && v[3] >= 1u)) break;
      __builtin_amdgcn_s_sleep(1);
    }
  }
  __syncthreads();
  // phase-anchor fence: drop stale (poison-era) lines before first loads
  if (tid < 64) __builtin_amdgcn_fence(__ATOMIC_ACQUIRE, "agent");
  __syncthreads();

  // ---- persistent time loop ----
  const int wave = tid >> 6, lane = tid & 63;
  const int msub = wave & 1;      // 32-row group
  const int kq   = wave >> 1;     // k-quarter (512)
  const unsigned a_off = (unsigned)((((bm*2 + msub) * 128) + kq * 32) * 1024 + lane * 16);
  const unsigned w_off = (unsigned)(LDS_W + (kq * 32) * 1024 + lane * 16);
  // C/D frag address pieces (32x32): col=lane&31, row=(r&3)+8*(r>>2)+4*(lane>>5)
  const int rowb = 4 * (lane >> 5);
  const int colc = lane & 31;
  float* reg1 = (float*)(lds + LDS_R1) + msub * 32 * PRE_STRIDE;
  float* reg3 = (float*)(lds + LDS_R3) + msub * 32 * PRE_STRIDE;

  for (int t = 0; t < TT; ++t) {
    const char* sb = sbufs + ((unsigned)(t & (NSB-1)) << 20);
    char*       sn = sbufs + ((unsigned)((t+1) & (NSB-1)) << 20);

    // ---- A-phase: 32 chunks, 16-slot register ring, vmcnt(8) phases ----
    f32x16 acc = {0,0,0,0,0,0,0,0,0,0,0,0,0,0,0,0};
    const char* ap = sb + a_off;
    s16x8 Ar[16];
    #pragma unroll
    for (int g = 0; g < 4; ++g) {
      const char* base = ap + g * 4096;
      LOAD_A(Ar[g*4+0], base, 0);
      LOAD_A(Ar[g*4+1], base, 1024);
      LOAD_A(Ar[g*4+2], base, 2048);
      LOAD_A(Ar[g*4+3], base, 3072);
    }
    asm volatile("s_waitcnt vmcnt(8)"
      : "+v"(Ar[0]),"+v"(Ar[1]),"+v"(Ar[2]),"+v"(Ar[3]),
        "+v"(Ar[4]),"+v"(Ar[5]),"+v"(Ar[6]),"+v"(Ar[7]));
    #pragma unroll
    for (int i = 0; i < 8; ++i) {
      s16x8 b = *(const s16x8*)(lds + w_off + i * 1024);
      acc = __builtin_amdgcn_mfma_f32_32x32x16_bf16(Ar[i], b, acc, 0, 0, 0);
    }
    {
      const char* b0 = ap + 16384;
      LOAD_A(Ar[0], b0, 0); LOAD_A(Ar[1], b0, 1024);
      LOAD_A(Ar[2], b0, 2048); LOAD_A(Ar[3], b0, 3072);
      const char* b1 = ap + 20480;
      LOAD_A(Ar[4], b1, 0); LOAD_A(Ar[5], b1, 1024);
      LOAD_A(Ar[6], b1, 2048); LOAD_A(Ar[7], b1, 3072);
    }
    asm volatile("s_waitcnt vmcnt(8)"
      : "+v"(Ar[8]),"+v"(Ar[9]),"+v"(Ar[10]),"+v"(Ar[11]),
        "+v"(Ar[12]),"+v"(Ar[13]),"+v"(Ar[14]),"+v"(Ar[15]));
    #pragma unroll
    for (int i = 8; i < 16; ++i) {
      s16x8 b = *(const s16x8*)(lds + w_off + i * 1024);
      acc = __builtin_amdgcn_mfma_f32_32x32x16_bf16(Ar[i], b, acc, 0, 0, 0);
    }
    {
      const char* b0 = ap + 24576;
      LOAD_A(Ar[8], b0, 0);  LOAD_A(Ar[9], b0, 1024);
      LOAD_A(Ar[10], b0, 2048); LOAD_A(Ar[11], b0, 3072);
      const char* b1 = ap + 28672;
      LOAD_A(Ar[12], b1, 0); LOAD_A(Ar[13], b1, 1024);
      LOAD_A(Ar[14], b1, 2048); LOAD_A(Ar[15], b1, 3072);
    }
    asm volatile("s_waitcnt vmcnt(8)"
      : "+v"(Ar[0]),"+v"(Ar[1]),"+v"(Ar[2]),"+v"(Ar[3]),
        "+v"(Ar[4]),"+v"(Ar[5]),"+v"(Ar[6]),"+v"(Ar[7]));
    #pragma unroll
    for (int i = 16; i < 24; ++i) {
      s16x8 b = *(const s16x8*)(lds + w_off + i * 1024);
      acc = __builtin_amdgcn_mfma_f32_32x32x16_bf16(Ar[i - 16], b, acc, 0, 0, 0);
    }
    asm volatile("s_waitcnt vmcnt(0)"
      : "+v"(Ar[8]),"+v"(Ar[9]),"+v"(Ar[10]),"+v"(Ar[11]),
        "+v"(Ar[12]),"+v"(Ar[13]),"+v"(Ar[14]),"+v"(Ar[15]));
    #pragma unroll
    for (int i = 24; i < 32; ++i) {
      s16x8 b = *(const s16x8*)(lds + w_off + i * 1024);
      acc = __builtin_amdgcn_mfma_f32_32x32x16_bf16(Ar[i - 16], b, acc, 0, 0, 0);
    }

    // ---- 2-phase race-free k-merge (bottom-of-loop sync replaces old SB1) ----
    if (kq == 1) {
      #pragma unroll
      for (int r = 0; r < 16; ++r) {
        int row = rowb + (r & 3) + 8 * (r >> 2);
        reg1[row * PRE_STRIDE + colc] = acc[r];
      }
    } else if (kq == 3) {
      #pragma unroll
      for (int r = 0; r < 16; ++r) {
        int row = rowb + (r & 3) + 8 * (r >> 2);
        reg3[row * PRE_STRIDE + colc] = acc[r];
      }
    }
    __syncthreads();   // SB2: phase-1 writes visible
    if (kq == 0) {
      #pragma unroll
      for (int r = 0; r < 16; ++r) {
        int row = rowb + (r & 3) + 8 * (r >> 2);
        reg1[row * PRE_STRIDE + colc] += acc[r];
      }
    } else if (kq == 2) {
      #pragma unroll
      for (int r = 0; r < 16; ++r) {
        int row = rowb + (r & 3) + 8 * (r >> 2);
        reg3[row * PRE_STRIDE + colc] += acc[r];
      }
    }
    __syncthreads();   // SB3: merge complete

    // ---- epilogue on waves 0-3; wave 4 polls the group concurrently ----
    if (tid < 256) {
      const float* p1 = (const float*)(lds + LDS_R1) + b_local * PRE_STRIDE + nl0;
      const float* p3 = (const float*)(lds + LDS_R3) + b_local * PRE_STRIDE + nl0;
      float4 u0 = *(const float4*)p1, u1 = *(const float4*)(p1 + 4);
      float4 v0 = *(const float4*)p3, v1 = *(const float4*)(p3 + 4);
      float pr[8] = {u0.x+v0.x, u0.y+v0.y, u0.z+v0.z, u0.w+v0.w,
                     u1.x+v1.x, u1.y+v1.y, u1.z+v1.z, u1.w+v1.w};
      float st[8];
      float d0 = 0.f, d1 = 0.f;
      #pragma unroll
      for (int j = 0; j < 8; ++j) {
        int nl = nl0 + j;
        float sg = 1.0f / (1.0f + __expf(-SLOPE * (pr[j] - cthr[nl])));
        float s = cmask[nl] * (cbias[nl] + sg);
        st[j] = s;
        d0 += s * cdec0[nl];
        d1 += s * cdec1[nl];
      }
      d0 += __shfl_xor(d0, 1); d0 += __shfl_xor(d0, 2);
      d1 += __shfl_xor(d1, 1); d1 += __shfl_xor(d1, 2);
      if (c4 == 0)
        store_u32_sys(&partials[((size_t)t*64 + bn)*256 + bg], pack2(d0, d1));
      if (t < TT - 1) {
        float x0n = x[(size_t)bg * TT + t + 1];
        float x1n = x[(size_t)(BB*TT) + bg * TT + t + 1];
        float sv[8];
        #pragma unroll
        for (int j = 0; j < 8; ++j) {
          int nl = nl0 + j;
          sv[j] = st[j] + cmask[nl] * (x0n * cenc0[nl] + x1n * cenc1[nl]);
        }
        u32x4 pk = { pack2(sv[0], sv[1]), pack2(sv[2], sv[3]),
                     pack2(sv[4], sv[5]), pack2(sv[6], sv[7]) };
        store_b128_sys(sn + s_slot, pk);
        // early per-wave post: drain own stores, post this wave's subflag
        asm volatile("s_waitcnt vmcnt(0)" ::: "memory");
        if ((tid & 63) == 0)
          __hip_atomic_store(&flags[(bm*64 + bn)*4 + (tid >> 6)], (unsigned)(t + 2),
                             __ATOMIC_RELAXED, __HIP_MEMORY_SCOPE_SYSTEM);
      }
    } else if ((tid >> 6) == 4 && t < TT - 1) {
      // single poller per block: whole group, one dwordx4 per lane
      const unsigned tv = (unsigned)(t + 2);
      const unsigned* fp = &flags[(bm*64 + (tid & 63)) * 4];
      for (;;) {
        u32x4 v;
        asm volatile("global_load_dwordx4 %0, %1, off sc0 sc1" : "=v"(v) : "v"(fp) : "memory");
        asm volatile("s_waitcnt vmcnt(0)" : "+v"(v));
        if (__all(v[0] >= tv && v[1] >= tv && v[2] >= tv && v[3] >= tv)) break;
        __builtin_amdgcn_s_sleep(1);
      }
    }
    if (t < TT - 1) {
      __syncthreads();   // release: group done (poller) + own epilogue done
      if (((t + 1) & (NSB - 1)) == 0) {   // rotation fence, before reuse-reads
        if (tid < 64) __builtin_amdgcn_fence(__ATOMIC_ACQUIRE, "agent");
        __syncthreads();
      }
    }
  }
}

// out[c][b][t] = sum_bn unpack(partials[t][bn][b])
__global__ __launch_bounds__(256)
void reduce_out_kernel(const unsigned* __restrict__ partials, float* __restrict__ out) {
  const int t = blockIdx.x;
  const int b = threadIdx.x;
  const unsigned* p = partials + (size_t)t * 64 * 256 + b;
  float s0 = 0.f, s1 = 0.f;
  #pragma unroll
  for (int bn = 0; bn < 64; ++bn) {
    unsigned v = p[bn * 256];
    union { unsigned u; float f; } lo, hi;
    lo.u = v << 16; hi.u = v & 0xffff0000u;
    s0 += lo.f; s1 += hi.f;
  }
  out[(size_t)b * TT + t] = s0;
  out[(size_t)(BB * TT) + (size_t)b * TT + t] = s1;
}

extern "C" void kernel_launch(void* const* d_in, const int* in_sizes, int n_in,
                              void* d_out, int out_size, void* d_ws, size_t ws_size,
                              hipStream_t stream) {
  const float* x      = (const float*)d_in[0];
  const float* state0 = (const float*)d_in[1];
  const float* mask   = (const float*)d_in[2];
  const float* enc    = (const float*)d_in[3];
  const float* dec    = (const float*)d_in[4];
  const float* W      = (const float*)d_in[5];
  const float* bias   = (const float*)d_in[6];
  const float* thr    = (const float*)d_in[7];
  float* out = (float*)d_out;
  char*  ws  = (char*)d_ws;

  (void)hipMemsetAsync(ws, 0, 4096, stream);   // subflags [4][64][4]

  (void)hipFuncSetAttribute((const void*)mc_integrator_kernel,
                            hipFuncAttributeMaxDynamicSharedMemorySize, LDS_TOTAL);

  void* args[] = { (void*)&x, (void*)&state0, (void*)&mask, (void*)&enc, (void*)&dec,
                   (void*)&W, (void*)&bias, (void*)&thr, (void*)&ws };
  (void)hipLaunchCooperativeKernel((const void*)mc_integrator_kernel,
                                   dim3(NBLK), dim3(NTH), args, (unsigned)LDS_TOTAL, stream);

  const unsigned* partials = (const unsigned*)(ws + WS_PART);
  reduce_out_kernel<<<dim3(TT), dim3(256), 0, stream>>>(partials, out);
}

// Round 13
// 1569.933 us; speedup vs baseline: 2.2922x; 1.7109x over previous
//
#include <hip/hip_runtime.h>

// Problem constants (ManyChannelsIntegrator: C=2, B=256, T=256, N=2048)
#define NN 2048
#define BB 256
#define TT 256
#define SLOPE 8.0f

#define NBLK 256   // 1 block per CU
#define NTH  512   // 8 waves: (msub 2) x (kq 4)
#define MT 64      // b-rows per block  (gM = 4)
#define NT 32      // n-cols per block  (gN = 64)
#define NSB 8      // S-buffer rotation depth (invalidate every NSB steps)

// LDS layout (bytes) — identical to R10 (1798 us kernel)
#define LDS_W    0                         // W in B-frag order (32x32x16): 128 chunks x 1 KB = 128 KB
#define PRE_STRIDE 36                      // fp32 words per row
#define LDS_R1   131072                    // [2 msub][32][36] fp32 — kq0+kq1 partial
#define LDS_R3   (LDS_R1 + 2*32*PRE_STRIDE*4)   // [2 msub][32][36] — kq2+kq3 partial
#define LDS_CONST (LDS_R3 + 2*32*PRE_STRIDE*4)
#define LDS_TOTAL (LDS_CONST + 7*32*4)          // 150400 < 160 KB

// ws layout (bytes)
// flags: ONE 128-B IC line per member — kills post-side line contention.
#define WS_FLAGS 0                        // [4 bm][64 member] x 128 B = 32 KB (memset 0)
#define WS_SBUF  32768                    // 8 x 1 MB S rotation, A-frag order (32x32)
#define WS_PART  (32768 + (8u<<20))       // u32-packed bf16 partials [T][64 bn][256 b]

typedef short s16x8 __attribute__((ext_vector_type(8)));      // 8 bf16 (4 VGPRs)
typedef float f32x16 __attribute__((ext_vector_type(16)));
typedef unsigned u32x4 __attribute__((ext_vector_type(4)));

__device__ __forceinline__ unsigned f2bf1(float f) {
  union { float f; unsigned u; } v; v.f = f;
  return (v.u + 0x7fffu + ((v.u >> 16) & 1u)) >> 16;   // RNE
}
__device__ __forceinline__ unsigned pack2(float a, float b) {
  return f2bf1(a) | (f2bf1(b) << 16);
}

// System-scope write-through stores (never dirty L1/L2 -> buffer_inv safe).
__device__ __forceinline__ void store_b128_sys(void* p, u32x4 v) {
  asm volatile("global_store_dwordx4 %0, %1, off sc0 sc1" :: "v"(p), "v"(v) : "memory");
}
__device__ __forceinline__ void store_u32_sys(void* p, unsigned v) {
  asm volatile("global_store_dword %0, %1, off sc0 sc1" :: "v"(p), "v"(v) : "memory");
}

// A-load: plain -> L1/L2-cached (R7/R10: L2 dedups the broadcast).
#define LOAD_A(dst, base, OFF) \
  asm volatile("global_load_dwordx4 %0, %1, off offset:" #OFF \
               : "=v"(dst) : "v"(base) : "memory")

// R10-style group barrier (64 blocks = 2 XCDs), with line-padded flags:
//  drain all stores -> block sync -> ONE flag store (own line) ->
//  wave 0 polls 64 member lines (parallel line fetches) -> sync.
// Optional agent-acquire fence every NSB steps (S rotation cadence).
__device__ __forceinline__ void grid_barrier(unsigned* flags, int gbase, int member,
                                             unsigned tval, bool do_inv) {
  asm volatile("s_waitcnt vmcnt(0)" ::: "memory");
  __syncthreads();
  const int tid = threadIdx.x;
  if (tid == 0)
    __hip_atomic_store(&flags[(gbase + member) * 32], tval,
                       __ATOMIC_RELAXED, __HIP_MEMORY_SCOPE_SYSTEM);
  if (tid < 64) {
    for (;;) {
      unsigned v = __hip_atomic_load(&flags[(gbase + tid) * 32],
                                     __ATOMIC_RELAXED, __HIP_MEMORY_SCOPE_SYSTEM);
      if (__all(v >= tval)) break;
      __builtin_amdgcn_s_sleep(1);
    }
  }
  __syncthreads();
  if (do_inv) {
    if (tid < 64) __builtin_amdgcn_fence(__ATOMIC_ACQUIRE, "agent");
    __syncthreads();
  }
}

__global__ __launch_bounds__(NTH, 2)
void mc_integrator_kernel(const float* __restrict__ x, const float* __restrict__ state0,
                          const float* __restrict__ mask, const float* __restrict__ enc,
                          const float* __restrict__ dec, const float* __restrict__ W,
                          const float* __restrict__ bias, const float* __restrict__ thr,
                          char* __restrict__ ws)
{
  extern __shared__ char lds[];
  const int tid = threadIdx.x;
  const int blk = blockIdx.x;
  // blk%8 ~ XCD: group bm occupies XCDs {2bm, 2bm+1} exclusively.
  const int xcd  = blk & 7;
  const int slot = blk >> 3;
  const int bm = xcd >> 1;                      // 0..3  (64-row strip of b)
  const int bn = slot + ((xcd & 1) << 5);       // 0..63 (32-col strip of n)

  unsigned* flags = (unsigned*)(ws + WS_FLAGS);   // member stride = 32 u32 (128 B)
  char* sbufs = ws + WS_SBUF;                     // 8 x 1 MB rotation
  unsigned* partials = (unsigned*)(ws + WS_PART);

  // ---- stage per-n constants ----
  float* cmask = (float*)(lds + LDS_CONST);
  float* cbias = cmask + 32;  float* cthr  = cbias + 32;
  float* cenc0 = cthr  + 32;  float* cenc1 = cenc0 + 32;
  float* cdec0 = cenc1 + 32;  float* cdec1 = cdec0 + 32;
  if (tid < 32) {
    int n = bn * NT + tid;
    cmask[tid] = mask[n];  cbias[tid] = bias[n];  cthr[tid] = thr[n];
    cenc0[tid] = enc[n];   cenc1[tid] = enc[NN + n];
    cdec0[tid] = dec[n];   cdec1[tid] = dec[NN + n];
  }

  // ---- one-time: W tile -> bf16, LDS, 32x32x16 B-frag order (R9-validated) ----
  for (int it = 0; it < 16; ++it) {
    int c = tid + it * NTH;              // 0..8191
    int n_local = c >> 8;                // 0..31
    int kc = c & 255;                    // 8-k unit
    int k0 = kc * 8;
    const float* src = W + (size_t)(bn * NT + n_local) * NN + k0;
    float4 lo = *(const float4*)src;
    float4 hi = *(const float4*)(src + 4);
    u32x4 pk = { pack2(lo.x, lo.y), pack2(lo.z, lo.w),
                 pack2(hi.x, hi.y), pack2(hi.z, hi.w) };
    int addr = (kc >> 1) * 1024 + (((kc & 1) << 5) + n_local) * 16;
    *(u32x4*)(lds + LDS_W + addr) = pk;
  }
  __syncthreads();

  // ---- per-thread epilogue roles ----
  const int b_local = (tid & 255) >> 2;          // 0..63
  const int c4      = tid & 3;                   // 8-col group of n
  const int bg      = bm * MT + b_local;
  const int nl0     = c4 * 8;
  // S A-frag slot (32x32, R9-validated)
  const int rg     = bg >> 5;
  const int kb16_s = bn * 2 + (c4 >> 1);
  const int lane_s = ((c4 & 1) << 5) | (bg & 31);
  const unsigned s_slot = (unsigned)((rg * 128 + kb16_s) * 1024 + lane_s * 16);

  // ---- build S_0 -> sbuf[0] ----
  if (tid < 256) {
    const float* s0 = state0 + (size_t)bg * NN + bn * NT + nl0;
    float4 lo = *(const float4*)s0;
    float4 hi = *(const float4*)(s0 + 4);
    float sv[8] = {lo.x, lo.y, lo.z, lo.w, hi.x, hi.y, hi.z, hi.w};
    float x0 = x[(size_t)bg * TT];
    float x1 = x[(size_t)(BB*TT) + bg * TT];
    #pragma unroll
    for (int j = 0; j < 8; ++j)
      sv[j] += cmask[nl0+j] * (x0 * cenc0[nl0+j] + x1 * cenc1[nl0+j]);
    u32x4 pk = { pack2(sv[0], sv[1]), pack2(sv[2], sv[3]),
                 pack2(sv[4], sv[5]), pack2(sv[6], sv[7]) };
    store_b128_sys(sbufs + s_slot, pk);
  }
  grid_barrier(flags, bm * 64, bn, 1, true);   // phase anchor: inv before step 0

  // ---- persistent time loop ----
  const int wave = tid >> 6, lane = tid & 63;
  const int msub = wave & 1;      // 32-row group
  const int kq   = wave >> 1;     // k-quarter (512)
  const unsigned a_off = (unsigned)((((bm*2 + msub) * 128) + kq * 32) * 1024 + lane * 16);
  const unsigned w_off = (unsigned)(LDS_W + (kq * 32) * 1024 + lane * 16);
  // C/D frag address pieces (32x32): col=lane&31, row=(r&3)+8*(r>>2)+4*(lane>>5)
  const int rowb = 4 * (lane >> 5);
  const int colc = lane & 31;
  float* reg1 = (float*)(lds + LDS_R1) + msub * 32 * PRE_STRIDE;
  float* reg3 = (float*)(lds + LDS_R3) + msub * 32 * PRE_STRIDE;

  for (int t = 0; t < TT; ++t) {
    const char* sb = sbufs + ((unsigned)(t & (NSB-1)) << 20);
    char*       sn = sbufs + ((unsigned)((t+1) & (NSB-1)) << 20);

    // ---- A-phase: 32 chunks, 16-slot register ring, vmcnt(8) phases ----
    f32x16 acc = {0,0,0,0,0,0,0,0,0,0,0,0,0,0,0,0};
    const char* ap = sb + a_off;
    s16x8 Ar[16];
    #pragma unroll
    for (int g = 0; g < 4; ++g) {
      const char* base = ap + g * 4096;
      LOAD_A(Ar[g*4+0], base, 0);
      LOAD_A(Ar[g*4+1], base, 1024);
      LOAD_A(Ar[g*4+2], base, 2048);
      LOAD_A(Ar[g*4+3], base, 3072);
    }
    asm volatile("s_waitcnt vmcnt(8)"
      : "+v"(Ar[0]),"+v"(Ar[1]),"+v"(Ar[2]),"+v"(Ar[3]),
        "+v"(Ar[4]),"+v"(Ar[5]),"+v"(Ar[6]),"+v"(Ar[7]));
    #pragma unroll
    for (int i = 0; i < 8; ++i) {
      s16x8 b = *(const s16x8*)(lds + w_off + i * 1024);
      acc = __builtin_amdgcn_mfma_f32_32x32x16_bf16(Ar[i], b, acc, 0, 0, 0);
    }
    {
      const char* b0 = ap + 16384;
      LOAD_A(Ar[0], b0, 0); LOAD_A(Ar[1], b0, 1024);
      LOAD_A(Ar[2], b0, 2048); LOAD_A(Ar[3], b0, 3072);
      const char* b1 = ap + 20480;
      LOAD_A(Ar[4], b1, 0); LOAD_A(Ar[5], b1, 1024);
      LOAD_A(Ar[6], b1, 2048); LOAD_A(Ar[7], b1, 3072);
    }
    asm volatile("s_waitcnt vmcnt(8)"
      : "+v"(Ar[8]),"+v"(Ar[9]),"+v"(Ar[10]),"+v"(Ar[11]),
        "+v"(Ar[12]),"+v"(Ar[13]),"+v"(Ar[14]),"+v"(Ar[15]));
    #pragma unroll
    for (int i = 8; i < 16; ++i) {
      s16x8 b = *(const s16x8*)(lds + w_off + i * 1024);
      acc = __builtin_amdgcn_mfma_f32_32x32x16_bf16(Ar[i], b, acc, 0, 0, 0);
    }
    {
      const char* b0 = ap + 24576;
      LOAD_A(Ar[8], b0, 0);  LOAD_A(Ar[9], b0, 1024);
      LOAD_A(Ar[10], b0, 2048); LOAD_A(Ar[11], b0, 3072);
      const char* b1 = ap + 28672;
      LOAD_A(Ar[12], b1, 0); LOAD_A(Ar[13], b1, 1024);
      LOAD_A(Ar[14], b1, 2048); LOAD_A(Ar[15], b1, 3072);
    }
    asm volatile("s_waitcnt vmcnt(8)"
      : "+v"(Ar[0]),"+v"(Ar[1]),"+v"(Ar[2]),"+v"(Ar[3]),
        "+v"(Ar[4]),"+v"(Ar[5]),"+v"(Ar[6]),"+v"(Ar[7]));
    #pragma unroll
    for (int i = 16; i < 24; ++i) {
      s16x8 b = *(const s16x8*)(lds + w_off + i * 1024);
      acc = __builtin_amdgcn_mfma_f32_32x32x16_bf16(Ar[i - 16], b, acc, 0, 0, 0);
    }
    asm volatile("s_waitcnt vmcnt(0)"
      : "+v"(Ar[8]),"+v"(Ar[9]),"+v"(Ar[10]),"+v"(Ar[11]),
        "+v"(Ar[12]),"+v"(Ar[13]),"+v"(Ar[14]),"+v"(Ar[15]));
    #pragma unroll
    for (int i = 24; i < 32; ++i) {
      s16x8 b = *(const s16x8*)(lds + w_off + i * 1024);
      acc = __builtin_amdgcn_mfma_f32_32x32x16_bf16(Ar[i - 16], b, acc, 0, 0, 0);
    }

    // ---- 2-phase race-free k-merge (R10) ----
    if (kq == 1) {
      #pragma unroll
      for (int r = 0; r < 16; ++r) {
        int row = rowb + (r & 3) + 8 * (r >> 2);
        reg1[row * PRE_STRIDE + colc] = acc[r];
      }
    } else if (kq == 3) {
      #pragma unroll
      for (int r = 0; r < 16; ++r) {
        int row = rowb + (r & 3) + 8 * (r >> 2);
        reg3[row * PRE_STRIDE + colc] = acc[r];
      }
    }
    __syncthreads();   // SB2: phase-1 writes visible
    if (kq == 0) {
      #pragma unroll
      for (int r = 0; r < 16; ++r) {
        int row = rowb + (r & 3) + 8 * (r >> 2);
        reg1[row * PRE_STRIDE + colc] += acc[r];
      }
    } else if (kq == 2) {
      #pragma unroll
      for (int r = 0; r < 16; ++r) {
        int row = rowb + (r & 3) + 8 * (r >> 2);
        reg3[row * PRE_STRIDE + colc] += acc[r];
      }
    }
    __syncthreads();   // SB3: merge complete

    // ---- epilogue (reordered): S-store FIRST, decoder work after ----
    float d0 = 0.f, d1 = 0.f;
    if (tid < 256) {
      const float* p1 = (const float*)(lds + LDS_R1) + b_local * PRE_STRIDE + nl0;
      const float* p3 = (const float*)(lds + LDS_R3) + b_local * PRE_STRIDE + nl0;
      float4 u0 = *(const float4*)p1, u1 = *(const float4*)(p1 + 4);
      float4 v0 = *(const float4*)p3, v1 = *(const float4*)(p3 + 4);
      // x loads issued early (compiler orders them before the S-store dep)
      float x0n = 0.f, x1n = 0.f;
      if (t < TT - 1) {
        x0n = x[(size_t)bg * TT + t + 1];
        x1n = x[(size_t)(BB*TT) + bg * TT + t + 1];
      }
      float pr[8] = {u0.x+v0.x, u0.y+v0.y, u0.z+v0.z, u0.w+v0.w,
                     u1.x+v1.x, u1.y+v1.y, u1.z+v1.z, u1.w+v1.w};
      float st[8];
      #pragma unroll
      for (int j = 0; j < 8; ++j) {
        int nl = nl0 + j;
        float sg = 1.0f / (1.0f + __expf(-SLOPE * (pr[j] - cthr[nl])));
        st[j] = cmask[nl] * (cbias[nl] + sg);
      }
      if (t < TT - 1) {
        float sv[8];
        #pragma unroll
        for (int j = 0; j < 8; ++j) {
          int nl = nl0 + j;
          sv[j] = st[j] + cmask[nl] * (x0n * cenc0[nl] + x1n * cenc1[nl]);
        }
        u32x4 pk = { pack2(sv[0], sv[1]), pack2(sv[2], sv[3]),
                     pack2(sv[4], sv[5]), pack2(sv[6], sv[7]) };
        store_b128_sys(sn + s_slot, pk);     // in flight during decoder VALU below
      }
      #pragma unroll
      for (int j = 0; j < 8; ++j) {
        int nl = nl0 + j;
        d0 += st[j] * cdec0[nl];
        d1 += st[j] * cdec1[nl];
      }
      d0 += __shfl_xor(d0, 1); d0 += __shfl_xor(d0, 2);
      d1 += __shfl_xor(d1, 1); d1 += __shfl_xor(d1, 2);
    }
    if (t < TT - 1)
      grid_barrier(flags, bm * 64, bn, (unsigned)(t + 2), ((t + 1) & (NSB-1)) == 0);
    // partials store AFTER the barrier — no intra-kernel consumer, so it
    // drains during the next step's GEMM instead of the critical-path drain.
    if (tid < 256 && c4 == 0)
      store_u32_sys(&partials[((size_t)t*64 + bn)*256 + bg], pack2(d0, d1));
  }
}

// out[c][b][t] = sum_bn unpack(partials[t][bn][b])
__global__ __launch_bounds__(256)
void reduce_out_kernel(const unsigned* __restrict__ partials, float* __restrict__ out) {
  const int t = blockIdx.x;
  const int b = threadIdx.x;
  const unsigned* p = partials + (size_t)t * 64 * 256 + b;
  float s0 = 0.f, s1 = 0.f;
  #pragma unroll
  for (int bn = 0; bn < 64; ++bn) {
    unsigned v = p[bn * 256];
    union { unsigned u; float f; } lo, hi;
    lo.u = v << 16; hi.u = v & 0xffff0000u;
    s0 += lo.f; s1 += hi.f;
  }
  out[(size_t)b * TT + t] = s0;
  out[(size_t)(BB * TT) + (size_t)b * TT + t] = s1;
}

extern "C" void kernel_launch(void* const* d_in, const int* in_sizes, int n_in,
                              void* d_out, int out_size, void* d_ws, size_t ws_size,
                              hipStream_t stream) {
  const float* x      = (const float*)d_in[0];
  const float* state0 = (const float*)d_in[1];
  const float* mask   = (const float*)d_in[2];
  const float* enc    = (const float*)d_in[3];
  const float* dec    = (const float*)d_in[4];
  const float* W      = (const float*)d_in[5];
  const float* bias   = (const float*)d_in[6];
  const float* thr    = (const float*)d_in[7];
  float* out = (float*)d_out;
  char*  ws  = (char*)d_ws;

  (void)hipMemsetAsync(ws, 0, 32768, stream);   // line-padded flags [4][64]x128B

  (void)hipFuncSetAttribute((const void*)mc_integrator_kernel,
                            hipFuncAttributeMaxDynamicSharedMemorySize, LDS_TOTAL);

  void* args[] = { (void*)&x, (void*)&state0, (void*)&mask, (void*)&enc, (void*)&dec,
                   (void*)&W, (void*)&bias, (void*)&thr, (void*)&ws };
  (void)hipLaunchCooperativeKernel((const void*)mc_integrator_kernel,
                                   dim3(NBLK), dim3(NTH), args, (unsigned)LDS_TOTAL, stream);

  const unsigned* partials = (const unsigned*)(ws + WS_PART);
  reduce_out_kernel<<<dim3(TT), dim3(256), 0, stream>>>(partials, out);
}